// Round 3
// baseline (751.228 us; speedup 1.0000x reference)
//
#include <hip/hip_runtime.h>

// ---------------------------------------------------------------------------
// DeformableTransformerEncoderLayer on MI355X (gfx950)
// B=4, LQ=13294, DM=256, DFFN=1024, NL=4, NH=8, NP=4, HD=32
// M = 53176 rows, padded tiles to Mp = 53248 = 416*128.
// Workspace-lean plan (~97 MB):
//   G1: value_bf = bf16(src) @ WvT + bv              (SRC=1, bf16 out)
//   G2: offaw    = bf16(src+pos) @ [Ws|Wa]T + [bs|ba] (SRC=2, bf16 out, N=384)
//   softmax16:   softmax over aw groups of 16 (bf16 in place)
//   sample:      attn_bf = MSDeformAttn(value, loc, aw)
//   G4: d_out = src + attn_bf @ WoT + bo             (fp32 + resid)
//   LN1: x <- LN(d_out)            (x overlays dead value+offaw regions)
//   4x { G5p: h = relu(bf16(x) @ W1T[p] + b1[p])     (h overlays dead attn_bf)
//        G6p: d_out = (p? d_out : x) + h @ W2T[:,p] + (p? 0 : b2) }
//   LN2: d_out = LN(d_out) in place
// ---------------------------------------------------------------------------

#define LQn   13294
#define MREAL 53176
#define MP    53248
#define MT    416

typedef __attribute__((ext_vector_type(8))) short short8;
typedef __attribute__((ext_vector_type(4))) float f32x4;

__device__ __forceinline__ short f2bf(float f) {
    unsigned u = __float_as_uint(f);
    unsigned r = (u + 0x7FFFu + ((u >> 16) & 1u)) >> 16;  // RNE
    return (short)r;
}
__device__ __forceinline__ float bf2f(short b) {
    return __uint_as_float(((unsigned)(unsigned short)b) << 16);
}

// ---------------------------------------------------------------------------
// Weight transpose + bf16 cast: WT[n*K + k] = bf16(W[k*N + n])
// ---------------------------------------------------------------------------
__global__ __launch_bounds__(256) void transpose_w(const float* __restrict__ W,
                                                   short* __restrict__ WT,
                                                   int K, int N) {
    const int i = blockIdx.x * 256 + threadIdx.x;
    if (i >= K * N) return;
    const int n = i / K, k = i - n * K;
    WT[i] = f2bf(W[(size_t)k * N + n]);
}

// bsa = [bs | ba]; zerob = 256 zeros (bias for FFN accumulation passes 1..3)
__global__ void prep_small_k(const float* __restrict__ bs,
                             const float* __restrict__ ba,
                             float* __restrict__ bsa,
                             float* __restrict__ zerob) {
    const int t = threadIdx.x;
    if (t < 256) { bsa[t] = bs[t]; zerob[t] = 0.f; }
    else if (t < 384) bsa[t] = ba[t - 256];
}

// ---------------------------------------------------------------------------
// bf16 MFMA GEMM. 128x128 tile, BK=32, 4 waves, 16x16x32 MFMA.
// SRC: 0 = A is bf16[M][K]; 1 = A is fp32 (convert); 2 = A+A2 fp32 (q=src+pos)
// EPI: 1 = bf16 out + bias; 2 = relu->bf16 + bias; 3 = fp32 + bias + resid
// A rows clamped to M-1 during staging (d_in arrays have exactly M rows).
// resid/C may alias (in-place accumulate): no __restrict__ on them.
// ---------------------------------------------------------------------------
template <int SRC>
__device__ __forceinline__ short8 lda8(const short* Ab, const float* Af,
                                       const float* A2, size_t idx) {
    if constexpr (SRC == 0) {
        return *(const short8*)(Ab + idx);
    } else {
        const float4 lo = *(const float4*)(Af + idx);
        const float4 hi = *(const float4*)(Af + idx + 4);
        float v[8] = {lo.x, lo.y, lo.z, lo.w, hi.x, hi.y, hi.z, hi.w};
        if constexpr (SRC == 2) {
            const float4 lo2 = *(const float4*)(A2 + idx);
            const float4 hi2 = *(const float4*)(A2 + idx + 4);
            v[0] += lo2.x; v[1] += lo2.y; v[2] += lo2.z; v[3] += lo2.w;
            v[4] += hi2.x; v[5] += hi2.y; v[6] += hi2.z; v[7] += hi2.w;
        }
        short8 r;
#pragma unroll
        for (int j = 0; j < 8; ++j) r[j] = f2bf(v[j]);
        return r;
    }
}

template <int SRC, int EPI>
__global__ __launch_bounds__(256) void gemm_bt(const short* __restrict__ Ab,
                                               const float* __restrict__ Af,
                                               const float* __restrict__ A2,
                                               const short* __restrict__ BT,
                                               const float* __restrict__ bias,
                                               const float* resid,
                                               void* C,
                                               int M, int K, int N,
                                               int ldb, int ldc) {
    __shared__ short lA[128 * 32];
    __shared__ short lB[128 * 32];
    const int t = threadIdx.x;
    const int m0 = blockIdx.x * 128, n0 = blockIdx.y * 128;
    const int wid = t >> 6, lane = t & 63;
    const int wr = wid >> 1, wc = wid & 1;
    const int quad = lane >> 4, l16 = lane & 15;

    f32x4 acc[4][4];
#pragma unroll
    for (int i = 0; i < 4; ++i)
#pragma unroll
        for (int j = 0; j < 4; ++j) acc[i][j] = (f32x4){0.f, 0.f, 0.f, 0.f};

    const int ar0 = t >> 2, ac0 = (t & 3) * 8;
    const int ar1 = ar0 + 64, ac1 = ac0;
    // clamp A rows so fp32 staging never reads past the real M rows of d_in
    const int arow0 = min(m0 + ar0, M - 1);
    const int arow1 = min(m0 + ar1, M - 1);

    for (int k0 = 0; k0 < K; k0 += 32) {
        const short8 va0 = lda8<SRC>(Ab, Af, A2, (size_t)arow0 * K + k0 + ac0);
        const short8 va1 = lda8<SRC>(Ab, Af, A2, (size_t)arow1 * K + k0 + ac1);
        const short8 vb0 = *(const short8*)(BT + (size_t)(n0 + ar0) * ldb + k0 + ac0);
        const short8 vb1 = *(const short8*)(BT + (size_t)(n0 + ar1) * ldb + k0 + ac1);
        __syncthreads();
        *(short8*)&lA[ar0 * 32 + ac0] = va0;
        *(short8*)&lA[ar1 * 32 + ac1] = va1;
        *(short8*)&lB[ar0 * 32 + ac0] = vb0;
        *(short8*)&lB[ar1 * 32 + ac1] = vb1;
        __syncthreads();
        short8 af[4], bfr[4];
#pragma unroll
        for (int mi = 0; mi < 4; ++mi)
            af[mi] = *(const short8*)&lA[(wr * 64 + mi * 16 + l16) * 32 + quad * 8];
#pragma unroll
        for (int ni = 0; ni < 4; ++ni)
            bfr[ni] = *(const short8*)&lB[(wc * 64 + ni * 16 + l16) * 32 + quad * 8];
#pragma unroll
        for (int mi = 0; mi < 4; ++mi)
#pragma unroll
            for (int ni = 0; ni < 4; ++ni)
                acc[mi][ni] = __builtin_amdgcn_mfma_f32_16x16x32_bf16(
                    af[mi], bfr[ni], acc[mi][ni], 0, 0, 0);
    }

#pragma unroll
    for (int ni = 0; ni < 4; ++ni) {
        const int gc = n0 + wc * 64 + ni * 16 + l16;
        const float bia = bias[gc];
#pragma unroll
        for (int mi = 0; mi < 4; ++mi) {
#pragma unroll
            for (int r = 0; r < 4; ++r) {
                const int gr = m0 + wr * 64 + mi * 16 + quad * 4 + r;
                if (gr < M) {
                    float v = acc[mi][ni][r] + bia;
                    if (EPI == 3) {
                        v += resid[(size_t)gr * ldc + gc];
                        ((float*)C)[(size_t)gr * ldc + gc] = v;
                    } else {
                        if (EPI == 2) v = fmaxf(v, 0.f);
                        ((short*)C)[(size_t)gr * ldc + gc] = f2bf(v);
                    }
                }
            }
        }
    }
}

// ---------------------------------------------------------------------------
// In-place softmax over 16 bf16 attention logits per (row, head).
// ---------------------------------------------------------------------------
__global__ __launch_bounds__(256) void softmax16_k(short* offaw) {
    const int t = blockIdx.x * 256 + threadIdx.x;
    if (t >= MREAL * 8) return;
    const int row = t >> 3, h = t & 7;
    short* p = offaw + (size_t)row * 384 + 256 + h * 16;
    const short8 a = *(const short8*)p;
    const short8 b = *(const short8*)(p + 8);
    float v[16];
#pragma unroll
    for (int j = 0; j < 8; ++j) { v[j] = bf2f(a[j]); v[j + 8] = bf2f(b[j]); }
    float m = v[0];
#pragma unroll
    for (int j = 1; j < 16; ++j) m = fmaxf(m, v[j]);
    float s = 0.f;
#pragma unroll
    for (int j = 0; j < 16; ++j) { v[j] = __expf(v[j] - m); s += v[j]; }
    const float inv = 1.f / s;
    short8 oa, ob;
#pragma unroll
    for (int j = 0; j < 8; ++j) {
        oa[j] = f2bf(v[j] * inv);
        ob[j] = f2bf(v[j + 8] * inv);
    }
    *(short8*)p = oa;
    *(short8*)(p + 8) = ob;
}

// ---------------------------------------------------------------------------
// MS deformable sampling. 4 threads per (row, head); each owns 8 of 32 dims.
// ---------------------------------------------------------------------------
__device__ __forceinline__ void acc_corner(float* acc, const short* p, float w) {
    const short8 v = *(const short8*)p;
#pragma unroll
    for (int j = 0; j < 8; ++j) acc[j] += w * bf2f(v[j]);
}

__global__ __launch_bounds__(256) void sample_k(const short* __restrict__ value,
                                                const short* __restrict__ offaw,
                                                const float* __restrict__ refp,
                                                short* __restrict__ attn) {
    const int t = blockIdx.x * 256 + threadIdx.x;
    const int grp = t >> 2, sub = t & 3;
    if (grp >= MREAL * 8) return;
    const int row = grp >> 3, h = grp & 7;
    const int b = row / LQn;
    const int L_[4] = {100, 50, 25, 13};
    const int O_[4] = {0, 10000, 12500, 13125};
    const short* op = offaw + (size_t)row * 384 + h * 32;
    const short* ap = offaw + (size_t)row * 384 + 256 + h * 16;
    const float* rp = refp + (size_t)row * 8;
    const int vcol = h * 32 + sub * 8;
    float acc[8];
#pragma unroll
    for (int j = 0; j < 8; ++j) acc[j] = 0.f;
#pragma unroll
    for (int l = 0; l < 4; ++l) {
        const int L = L_[l];
        const float Lf = (float)L;
        const long long lbase = (long long)b * LQn + O_[l];
        const float rx = rp[l * 2 + 0], ry = rp[l * 2 + 1];
#pragma unroll
        for (int p = 0; p < 4; ++p) {
            // pixel = ref*L + off - 0.5
            const float x = rx * Lf + bf2f(op[l * 8 + p * 2 + 0]) - 0.5f;
            const float y = ry * Lf + bf2f(op[l * 8 + p * 2 + 1]) - 0.5f;
            const float xf = floorf(x), yf = floorf(y);
            const int ix = (int)xf, iy = (int)yf;
            const float fx = x - xf, fy = y - yf;
            const float aw = bf2f(ap[l * 4 + p]);
            const float gx0 = 1.f - fx, gy0 = 1.f - fy;
            const bool vx0 = ((unsigned)ix < (unsigned)L);
            const bool vx1 = ((unsigned)(ix + 1) < (unsigned)L);
            const bool vy0 = ((unsigned)iy < (unsigned)L);
            const bool vy1 = ((unsigned)(iy + 1) < (unsigned)L);
            const short* base = value + (lbase + (long long)iy * L + ix) * 256 + vcol;
            if (vy0 && vx0) acc_corner(acc, base, gx0 * gy0 * aw);
            if (vy0 && vx1) acc_corner(acc, base + 256, fx * gy0 * aw);
            if (vy1 && vx0) acc_corner(acc, base + (long long)L * 256, gx0 * fy * aw);
            if (vy1 && vx1) acc_corner(acc, base + (long long)L * 256 + 256, fx * fy * aw);
        }
    }
    short8 o;
#pragma unroll
    for (int j = 0; j < 8; ++j) o[j] = f2bf(acc[j]);
    *(short8*)(attn + (size_t)row * 256 + vcol) = o;
}

// ---------------------------------------------------------------------------
// Row LayerNorm over 256 cols. One wave per row, float4 per lane.
// Safe in place: each lane reads its float4 before writing; shfl reductions.
// ---------------------------------------------------------------------------
__global__ __launch_bounds__(256) void ln_rows(const float* in,
                                               const float* __restrict__ g,
                                               const float* __restrict__ be,
                                               float* outf, int M) {
    const int row = blockIdx.x * 4 + (threadIdx.x >> 6);
    if (row >= M) return;
    const int lane = threadIdx.x & 63;
    const float4 v = ((const float4*)(in + (size_t)row * 256))[lane];
    float s = v.x + v.y + v.z + v.w;
#pragma unroll
    for (int o = 32; o > 0; o >>= 1) s += __shfl_xor(s, o);
    const float mean = s * (1.0f / 256.0f);
    const float dx = v.x - mean, dy = v.y - mean, dz = v.z - mean, dw = v.w - mean;
    float q = dx * dx + dy * dy + dz * dz + dw * dw;
#pragma unroll
    for (int o = 32; o > 0; o >>= 1) q += __shfl_xor(q, o);
    const float rstd = rsqrtf(q * (1.0f / 256.0f) + 1e-5f);
    const float4 gv = ((const float4*)g)[lane];
    const float4 bv = ((const float4*)be)[lane];
    float4 o4;
    o4.x = dx * rstd * gv.x + bv.x;
    o4.y = dy * rstd * gv.y + bv.y;
    o4.z = dz * rstd * gv.z + bv.z;
    o4.w = dw * rstd * gv.w + bv.w;
    ((float4*)(outf + (size_t)row * 256))[lane] = o4;
}

// ---------------------------------------------------------------------------
extern "C" void kernel_launch(void* const* d_in, const int* in_sizes, int n_in,
                              void* d_out, int out_size, void* d_ws, size_t ws_size,
                              hipStream_t stream) {
    (void)in_sizes; (void)n_in; (void)out_size; (void)ws_size;
    const float* src  = (const float*)d_in[0];
    const float* pos  = (const float*)d_in[1];
    const float* refp = (const float*)d_in[2];
    const float* Wv = (const float*)d_in[5];
    const float* bv = (const float*)d_in[6];
    const float* Ws = (const float*)d_in[7];
    const float* bs = (const float*)d_in[8];
    const float* Wa = (const float*)d_in[9];
    const float* ba = (const float*)d_in[10];
    const float* Wo = (const float*)d_in[11];
    const float* bo = (const float*)d_in[12];
    const float* W1 = (const float*)d_in[13];
    const float* b1 = (const float*)d_in[14];
    const float* W2 = (const float*)d_in[15];
    const float* b2 = (const float*)d_in[16];
    const float* g1 = (const float*)d_in[17];
    const float* be1 = (const float*)d_in[18];
    const float* g2 = (const float*)d_in[19];
    const float* be2 = (const float*)d_in[20];

    char* ws = (char*)d_ws;
    size_t off = 0;
    auto take = [&](size_t bytes) {
        char* p = ws + off;
        off += (bytes + 255) & ~(size_t)255;
        return p;
    };
    short* WvT  = (short*)take(256 * 256 * 2);
    short* WsaT = (short*)take(384 * 256 * 2);
    short* WoT  = (short*)take(256 * 256 * 2);
    short* W1T  = (short*)take(1024 * 256 * 2);
    short* W2T  = (short*)take(256 * 1024 * 2);
    float* bsa  = (float*)take(384 * 4);
    float* zerob = (float*)take(256 * 4);
    short* value_bf = (short*)take((size_t)MP * 256 * 2);  // 1Q; x part 1
    short* offaw    = (short*)take((size_t)MP * 384 * 2);  // 1.5Q; x part 2
    short* attn_bf  = (short*)take((size_t)MP * 256 * 2);  // 1Q; reused as h
    // total ~96.9 MB

    float* x = (float*)value_bf;   // MP*256 fp32 = MP*1024 B <= value+offaw (MP*1280 B)
    short* h = attn_bf;            // MP*256 bf16
    float* z = (float*)d_out;      // y / z / final output, fp32

    // Weight prep
    transpose_w<<<(256 * 256) / 256, 256, 0, stream>>>(Wv, WvT, 256, 256);
    transpose_w<<<(256 * 256) / 256, 256, 0, stream>>>(Ws, WsaT, 256, 256);
    transpose_w<<<(256 * 128) / 256, 256, 0, stream>>>(Wa, WsaT + 256 * 256, 256, 128);
    transpose_w<<<(256 * 256) / 256, 256, 0, stream>>>(Wo, WoT, 256, 256);
    transpose_w<<<(256 * 1024) / 256, 256, 0, stream>>>(W1, W1T, 256, 1024);
    transpose_w<<<(1024 * 256) / 256, 256, 0, stream>>>(W2, W2T, 1024, 256);
    prep_small_k<<<1, 384, 0, stream>>>(bs, ba, bsa, zerob);

    // G1: value = bf16(src) @ WvT + bv
    gemm_bt<1, 1><<<dim3(MT, 2), 256, 0, stream>>>(
        nullptr, src, nullptr, WvT, bv, nullptr, value_bf, MREAL, 256, 256, 256, 256);
    // G2: offaw = bf16(src+pos) @ WsaT + bsa
    gemm_bt<2, 1><<<dim3(MT, 3), 256, 0, stream>>>(
        nullptr, src, pos, WsaT, bsa, nullptr, offaw, MREAL, 256, 384, 256, 384);
    softmax16_k<<<(MREAL * 8 + 255) / 256, 256, 0, stream>>>(offaw);
    // Deformable sampling
    sample_k<<<(MREAL * 32) / 256, 256, 0, stream>>>(value_bf, offaw, refp, attn_bf);
    // G4: d_out = src + attn @ WoT + bo
    gemm_bt<0, 3><<<dim3(MT, 2), 256, 0, stream>>>(
        attn_bf, nullptr, nullptr, WoT, bo, src, z, MREAL, 256, 256, 256, 256);
    // LN1: x = LN(d_out)
    ln_rows<<<MREAL / 4, 256, 0, stream>>>(z, g1, be1, x, MREAL);
    // FFN in 4 column-quarters of DFFN; bias b2 only on pass 0
    for (int p = 0; p < 4; ++p) {
        gemm_bt<1, 2><<<dim3(MT, 2), 256, 0, stream>>>(
            nullptr, x, nullptr, W1T + (size_t)p * 256 * 256, b1 + p * 256, nullptr,
            h, MREAL, 256, 256, 256, 256);
        gemm_bt<0, 3><<<dim3(MT, 2), 256, 0, stream>>>(
            h, nullptr, nullptr, W2T + p * 256, (p == 0 ? b2 : zerob),
            (p == 0 ? x : z), z, MREAL, 256, 256, 1024, 256);
    }
    // LN2 in place
    ln_rows<<<MREAL / 4, 256, 0, stream>>>(z, g2, be2, z, MREAL);
}

// Round 4
// 642.428 us; speedup vs baseline: 1.1694x; 1.1694x over previous
//
#include <hip/hip_runtime.h>

// ---------------------------------------------------------------------------
// DeformableTransformerEncoderLayer on MI355X (gfx950)
// B=4, LQ=13294, DM=256, DFFN=1024, NL=4, NH=8, NP=4, HD=32
// M = 53176 rows, padded tiles to Mp = 53248 = 416*128.
// Round 4:
//  - value stored HEAD-MAJOR [B][NH][LQ][HD] so each bilinear corner is a
//    contiguous 64B and the (x,x+1) pair usually shares one 128B line.
//  - FFN in 2 half-passes (DFFN 512+512), x kept bf16 only, h_half overlays
//    dead offaw+attn regions.
// Pipeline:
//   G1: value_h = bf16(src) @ WvT + bv        (head-major scatter epilogue)
//   G2: offaw   = bf16(src+pos) @ [Ws|Wa]T + [bs|ba]  (bf16, N=384)
//   softmax16 (in place)  ->  sample -> attn_bf
//   G4: z(d_out) = src + attn_bf @ WoT + bo   (fp32 + resid)
//   LN1: x_bf <- LN(z)                        (bf16 out, overlays value)
//   2x { G5p: h = relu(x_bf @ W1T[p] + b1[p])     (h overlays offaw+attn)
//        G6p: z = resid + h @ W2T[:,p] (+b2 on p0; resid = x_bf on p0 else z) }
//   LN2: d_out = LN(z) in place
// Workspace ~97 MB.
// ---------------------------------------------------------------------------

#define LQn   13294
#define MREAL 53176
#define MP    53248
#define MT    416

typedef __attribute__((ext_vector_type(8))) short short8;
typedef __attribute__((ext_vector_type(4))) short short4v;
typedef __attribute__((ext_vector_type(4))) float f32x4;

__device__ __forceinline__ short f2bf(float f) {
    unsigned u = __float_as_uint(f);
    unsigned r = (u + 0x7FFFu + ((u >> 16) & 1u)) >> 16;  // RNE
    return (short)r;
}
__device__ __forceinline__ float bf2f(short b) {
    return __uint_as_float(((unsigned)(unsigned short)b) << 16);
}

// ---------------------------------------------------------------------------
__global__ __launch_bounds__(256) void transpose_w(const float* __restrict__ W,
                                                   short* __restrict__ WT,
                                                   int K, int N) {
    const int i = blockIdx.x * 256 + threadIdx.x;
    if (i >= K * N) return;
    const int n = i / K, k = i - n * K;
    WT[i] = f2bf(W[(size_t)k * N + n]);
}

__global__ void prep_small_k(const float* __restrict__ bs,
                             const float* __restrict__ ba,
                             float* __restrict__ bsa,
                             float* __restrict__ zerob) {
    const int t = threadIdx.x;
    if (t < 256) { bsa[t] = bs[t]; zerob[t] = 0.f; }
    else if (t < 384) bsa[t] = ba[t - 256];
}

// ---------------------------------------------------------------------------
// bf16 MFMA GEMM. 128x128 tile, BK=32, 4 waves, 16x16x32 MFMA.
// SRC: 0 = A bf16[M][K]; 1 = A fp32 (convert); 2 = A+A2 fp32 (q=src+pos)
// EPI: 1 = bf16+bias; 2 = relu->bf16+bias; 3 = fp32+bias+fp32 resid;
//      4 = fp32+bias+bf16 resid; 5 = bf16+bias scattered head-major
// ---------------------------------------------------------------------------
template <int SRC>
__device__ __forceinline__ short8 lda8(const short* Ab, const float* Af,
                                       const float* A2, size_t idx) {
    if constexpr (SRC == 0) {
        return *(const short8*)(Ab + idx);
    } else {
        const float4 lo = *(const float4*)(Af + idx);
        const float4 hi = *(const float4*)(Af + idx + 4);
        float v[8] = {lo.x, lo.y, lo.z, lo.w, hi.x, hi.y, hi.z, hi.w};
        if constexpr (SRC == 2) {
            const float4 lo2 = *(const float4*)(A2 + idx);
            const float4 hi2 = *(const float4*)(A2 + idx + 4);
            v[0] += lo2.x; v[1] += lo2.y; v[2] += lo2.z; v[3] += lo2.w;
            v[4] += hi2.x; v[5] += hi2.y; v[6] += hi2.z; v[7] += hi2.w;
        }
        short8 r;
#pragma unroll
        for (int j = 0; j < 8; ++j) r[j] = f2bf(v[j]);
        return r;
    }
}

template <int SRC, int EPI>
__global__ __launch_bounds__(256) void gemm_bt(const short* __restrict__ Ab,
                                               const float* __restrict__ Af,
                                               const float* __restrict__ A2,
                                               const short* __restrict__ BT,
                                               const float* __restrict__ bias,
                                               const void* resid,
                                               void* C,
                                               int M, int K, int N,
                                               int ldb, int ldc) {
    __shared__ short lA[128 * 32];
    __shared__ short lB[128 * 32];
    const int t = threadIdx.x;
    const int m0 = blockIdx.x * 128, n0 = blockIdx.y * 128;
    const int wid = t >> 6, lane = t & 63;
    const int wr = wid >> 1, wc = wid & 1;
    const int quad = lane >> 4, l16 = lane & 15;

    f32x4 acc[4][4];
#pragma unroll
    for (int i = 0; i < 4; ++i)
#pragma unroll
        for (int j = 0; j < 4; ++j) acc[i][j] = (f32x4){0.f, 0.f, 0.f, 0.f};

    const int ar0 = t >> 2, ac0 = (t & 3) * 8;
    const int ar1 = ar0 + 64, ac1 = ac0;
    const int arow0 = min(m0 + ar0, M - 1);
    const int arow1 = min(m0 + ar1, M - 1);

    for (int k0 = 0; k0 < K; k0 += 32) {
        const short8 va0 = lda8<SRC>(Ab, Af, A2, (size_t)arow0 * K + k0 + ac0);
        const short8 va1 = lda8<SRC>(Ab, Af, A2, (size_t)arow1 * K + k0 + ac1);
        const short8 vb0 = *(const short8*)(BT + (size_t)(n0 + ar0) * ldb + k0 + ac0);
        const short8 vb1 = *(const short8*)(BT + (size_t)(n0 + ar1) * ldb + k0 + ac1);
        __syncthreads();
        *(short8*)&lA[ar0 * 32 + ac0] = va0;
        *(short8*)&lA[ar1 * 32 + ac1] = va1;
        *(short8*)&lB[ar0 * 32 + ac0] = vb0;
        *(short8*)&lB[ar1 * 32 + ac1] = vb1;
        __syncthreads();
        short8 af[4], bfr[4];
#pragma unroll
        for (int mi = 0; mi < 4; ++mi)
            af[mi] = *(const short8*)&lA[(wr * 64 + mi * 16 + l16) * 32 + quad * 8];
#pragma unroll
        for (int ni = 0; ni < 4; ++ni)
            bfr[ni] = *(const short8*)&lB[(wc * 64 + ni * 16 + l16) * 32 + quad * 8];
#pragma unroll
        for (int mi = 0; mi < 4; ++mi)
#pragma unroll
            for (int ni = 0; ni < 4; ++ni)
                acc[mi][ni] = __builtin_amdgcn_mfma_f32_16x16x32_bf16(
                    af[mi], bfr[ni], acc[mi][ni], 0, 0, 0);
    }

#pragma unroll
    for (int ni = 0; ni < 4; ++ni) {
        const int gc = n0 + wc * 64 + ni * 16 + l16;
        const float bia = bias[gc];
#pragma unroll
        for (int mi = 0; mi < 4; ++mi) {
#pragma unroll
            for (int r = 0; r < 4; ++r) {
                const int gr = m0 + wr * 64 + mi * 16 + quad * 4 + r;
                if (gr < M) {
                    float v = acc[mi][ni][r] + bia;
                    if (EPI == 3) {
                        v += ((const float*)resid)[(size_t)gr * ldc + gc];
                        ((float*)C)[(size_t)gr * ldc + gc] = v;
                    } else if (EPI == 4) {
                        v += bf2f(((const short*)resid)[(size_t)gr * ldc + gc]);
                        ((float*)C)[(size_t)gr * ldc + gc] = v;
                    } else if (EPI == 5) {
                        // head-major scatter: [B][NH][LQ][HD]
                        const int b = gr / LQn, s = gr - b * LQn;
                        const int h = gc >> 5, d = gc & 31;
                        ((short*)C)[(((size_t)b * 8 + h) * LQn + s) * 32 + d] = f2bf(v);
                    } else {
                        if (EPI == 2) v = fmaxf(v, 0.f);
                        ((short*)C)[(size_t)gr * ldc + gc] = f2bf(v);
                    }
                }
            }
        }
    }
}

// ---------------------------------------------------------------------------
// In-place softmax over 16 bf16 attention logits per (row, head).
// ---------------------------------------------------------------------------
__global__ __launch_bounds__(256) void softmax16_k(short* offaw) {
    const int t = blockIdx.x * 256 + threadIdx.x;
    if (t >= MREAL * 8) return;
    const int row = t >> 3, h = t & 7;
    short* p = offaw + (size_t)row * 384 + 256 + h * 16;
    const short8 a = *(const short8*)p;
    const short8 b = *(const short8*)(p + 8);
    float v[16];
#pragma unroll
    for (int j = 0; j < 8; ++j) { v[j] = bf2f(a[j]); v[j + 8] = bf2f(b[j]); }
    float m = v[0];
#pragma unroll
    for (int j = 1; j < 16; ++j) m = fmaxf(m, v[j]);
    float s = 0.f;
#pragma unroll
    for (int j = 0; j < 16; ++j) { v[j] = __expf(v[j] - m); s += v[j]; }
    const float inv = 1.f / s;
    short8 oa, ob;
#pragma unroll
    for (int j = 0; j < 8; ++j) {
        oa[j] = f2bf(v[j] * inv);
        ob[j] = f2bf(v[j + 8] * inv);
    }
    *(short8*)p = oa;
    *(short8*)(p + 8) = ob;
}

// ---------------------------------------------------------------------------
// MS deformable sampling, head-major value [B][NH][LQ][HD].
// 4 threads per (row, head); each owns 8 of 32 dims.
// ---------------------------------------------------------------------------
__device__ __forceinline__ void acc_corner(float* acc, const short* p, float w) {
    const short8 v = *(const short8*)p;
#pragma unroll
    for (int j = 0; j < 8; ++j) acc[j] += w * bf2f(v[j]);
}

__global__ __launch_bounds__(256) void sample_k(const short* __restrict__ value,
                                                const short* __restrict__ offaw,
                                                const float* __restrict__ refp,
                                                short* __restrict__ attn) {
    const int t = blockIdx.x * 256 + threadIdx.x;
    const int grp = t >> 2, sub = t & 3;
    if (grp >= MREAL * 8) return;
    const int row = grp >> 3, h = grp & 7;
    const int b = row / LQn;
    const int L_[4] = {100, 50, 25, 13};
    const int O_[4] = {0, 10000, 12500, 13125};
    const short* op = offaw + (size_t)row * 384 + h * 32;
    const short* ap = offaw + (size_t)row * 384 + 256 + h * 16;
    const float* rp = refp + (size_t)row * 8;
    // head plane base: value[((b*8+h)*LQn + spatial)*32]
    const short* vplane = value + ((size_t)(b * 8 + h) * LQn) * 32 + sub * 8;
    float acc[8];
#pragma unroll
    for (int j = 0; j < 8; ++j) acc[j] = 0.f;
#pragma unroll
    for (int l = 0; l < 4; ++l) {
        const int L = L_[l];
        const float Lf = (float)L;
        const short* vlev = vplane + (size_t)O_[l] * 32;
        const float rx = rp[l * 2 + 0], ry = rp[l * 2 + 1];
#pragma unroll
        for (int p = 0; p < 4; ++p) {
            const float x = rx * Lf + bf2f(op[l * 8 + p * 2 + 0]) - 0.5f;
            const float y = ry * Lf + bf2f(op[l * 8 + p * 2 + 1]) - 0.5f;
            const float xf = floorf(x), yf = floorf(y);
            const int ix = (int)xf, iy = (int)yf;
            const float fx = x - xf, fy = y - yf;
            const float aw = bf2f(ap[l * 4 + p]);
            const float gx0 = 1.f - fx, gy0 = 1.f - fy;
            const bool vx0 = ((unsigned)ix < (unsigned)L);
            const bool vx1 = ((unsigned)(ix + 1) < (unsigned)L);
            const bool vy0 = ((unsigned)iy < (unsigned)L);
            const bool vy1 = ((unsigned)(iy + 1) < (unsigned)L);
            const short* base = vlev + ((long long)iy * L + ix) * 32;
            if (vy0 && vx0) acc_corner(acc, base, gx0 * gy0 * aw);
            if (vy0 && vx1) acc_corner(acc, base + 32, fx * gy0 * aw);
            if (vy1 && vx0) acc_corner(acc, base + (long long)L * 32, gx0 * fy * aw);
            if (vy1 && vx1) acc_corner(acc, base + (long long)L * 32 + 32, fx * fy * aw);
        }
    }
    short8 o;
#pragma unroll
    for (int j = 0; j < 8; ++j) o[j] = f2bf(acc[j]);
    *(short8*)(attn + (size_t)row * 256 + h * 32 + sub * 8) = o;
}

// ---------------------------------------------------------------------------
// Row LayerNorm over 256 cols. One wave per row, float4 per lane.
// OUT_BF=0: fp32 out (in-place safe). OUT_BF=1: bf16 out only.
// ---------------------------------------------------------------------------
template <int OUT_BF>
__global__ __launch_bounds__(256) void ln_rows(const float* in,
                                               const float* __restrict__ g,
                                               const float* __restrict__ be,
                                               float* outf, short* outb, int M) {
    const int row = blockIdx.x * 4 + (threadIdx.x >> 6);
    if (row >= M) return;
    const int lane = threadIdx.x & 63;
    const float4 v = ((const float4*)(in + (size_t)row * 256))[lane];
    float s = v.x + v.y + v.z + v.w;
#pragma unroll
    for (int o = 32; o > 0; o >>= 1) s += __shfl_xor(s, o);
    const float mean = s * (1.0f / 256.0f);
    const float dx = v.x - mean, dy = v.y - mean, dz = v.z - mean, dw = v.w - mean;
    float q = dx * dx + dy * dy + dz * dz + dw * dw;
#pragma unroll
    for (int o = 32; o > 0; o >>= 1) q += __shfl_xor(q, o);
    const float rstd = rsqrtf(q * (1.0f / 256.0f) + 1e-5f);
    const float4 gv = ((const float4*)g)[lane];
    const float4 bv = ((const float4*)be)[lane];
    float4 o4;
    o4.x = dx * rstd * gv.x + bv.x;
    o4.y = dy * rstd * gv.y + bv.y;
    o4.z = dz * rstd * gv.z + bv.z;
    o4.w = dw * rstd * gv.w + bv.w;
    if (OUT_BF) {
        short4v ob;
        ob.x = f2bf(o4.x); ob.y = f2bf(o4.y); ob.z = f2bf(o4.z); ob.w = f2bf(o4.w);
        ((short4v*)(outb + (size_t)row * 256))[lane] = ob;
    } else {
        ((float4*)(outf + (size_t)row * 256))[lane] = o4;
    }
}

// ---------------------------------------------------------------------------
extern "C" void kernel_launch(void* const* d_in, const int* in_sizes, int n_in,
                              void* d_out, int out_size, void* d_ws, size_t ws_size,
                              hipStream_t stream) {
    (void)in_sizes; (void)n_in; (void)out_size; (void)ws_size;
    const float* src  = (const float*)d_in[0];
    const float* pos  = (const float*)d_in[1];
    const float* refp = (const float*)d_in[2];
    const float* Wv = (const float*)d_in[5];
    const float* bv = (const float*)d_in[6];
    const float* Ws = (const float*)d_in[7];
    const float* bs = (const float*)d_in[8];
    const float* Wa = (const float*)d_in[9];
    const float* ba = (const float*)d_in[10];
    const float* Wo = (const float*)d_in[11];
    const float* bo = (const float*)d_in[12];
    const float* W1 = (const float*)d_in[13];
    const float* b1 = (const float*)d_in[14];
    const float* W2 = (const float*)d_in[15];
    const float* b2 = (const float*)d_in[16];
    const float* g1 = (const float*)d_in[17];
    const float* be1 = (const float*)d_in[18];
    const float* g2 = (const float*)d_in[19];
    const float* be2 = (const float*)d_in[20];

    char* ws = (char*)d_ws;
    size_t off = 0;
    auto take = [&](size_t bytes) {
        char* p = ws + off;
        off += (bytes + 255) & ~(size_t)255;
        return p;
    };
    short* WvT  = (short*)take(256 * 256 * 2);
    short* WsaT = (short*)take(384 * 256 * 2);
    short* WoT  = (short*)take(256 * 256 * 2);
    short* W1T  = (short*)take(1024 * 256 * 2);
    short* W2T  = (short*)take(256 * 1024 * 2);
    float* bsa  = (float*)take(384 * 4);
    float* zerob = (float*)take(256 * 4);
    short* value_h = (short*)take((size_t)MP * 256 * 2);  // head-major value; later x_bf
    short* offaw   = (short*)take((size_t)MP * 384 * 2);  // later h_half part 1
    short* attn_bf = (short*)take((size_t)MP * 256 * 2);  // later h_half part 2
    // total ~96.9 MB

    short* x_bf = value_h;         // after sampling, value dead
    short* h    = offaw;           // h_half 54.5 MB spans offaw(40.9)+attn(27.3)
    float* z    = (float*)d_out;

    // Weight prep
    transpose_w<<<(256 * 256) / 256, 256, 0, stream>>>(Wv, WvT, 256, 256);
    transpose_w<<<(256 * 256) / 256, 256, 0, stream>>>(Ws, WsaT, 256, 256);
    transpose_w<<<(256 * 128) / 256, 256, 0, stream>>>(Wa, WsaT + 256 * 256, 256, 128);
    transpose_w<<<(256 * 256) / 256, 256, 0, stream>>>(Wo, WoT, 256, 256);
    transpose_w<<<(256 * 1024) / 256, 256, 0, stream>>>(W1, W1T, 256, 1024);
    transpose_w<<<(1024 * 256) / 256, 256, 0, stream>>>(W2, W2T, 1024, 256);
    prep_small_k<<<1, 384, 0, stream>>>(bs, ba, bsa, zerob);

    // G1: value (head-major) = bf16(src) @ WvT + bv
    gemm_bt<1, 5><<<dim3(MT, 2), 256, 0, stream>>>(
        nullptr, src, nullptr, WvT, bv, nullptr, value_h, MREAL, 256, 256, 256, 256);
    // G2: offaw = bf16(src+pos) @ WsaT + bsa
    gemm_bt<2, 1><<<dim3(MT, 3), 256, 0, stream>>>(
        nullptr, src, pos, WsaT, bsa, nullptr, offaw, MREAL, 256, 384, 256, 384);
    softmax16_k<<<(MREAL * 8 + 255) / 256, 256, 0, stream>>>(offaw);
    // Deformable sampling
    sample_k<<<(MREAL * 32) / 256, 256, 0, stream>>>(value_h, offaw, refp, attn_bf);
    // G4: z = src + attn @ WoT + bo
    gemm_bt<0, 3><<<dim3(MT, 2), 256, 0, stream>>>(
        attn_bf, nullptr, nullptr, WoT, bo, src, z, MREAL, 256, 256, 256, 256);
    // LN1: x_bf = LN(z)   (bf16 only)
    ln_rows<1><<<(MREAL + 3) / 4, 256, 0, stream>>>(z, g1, be1, nullptr, x_bf, MREAL);
    // FFN in 2 half-passes over DFFN
    for (int p = 0; p < 2; ++p) {
        gemm_bt<0, 2><<<dim3(MT, 4), 256, 0, stream>>>(
            x_bf, nullptr, nullptr, W1T + (size_t)p * 512 * 256, b1 + p * 512,
            nullptr, h, MREAL, 256, 512, 256, 512);
        if (p == 0)
            gemm_bt<0, 4><<<dim3(MT, 2), 256, 0, stream>>>(
                h, nullptr, nullptr, W2T + 0, b2, x_bf, z,
                MREAL, 512, 256, 1024, 256);
        else
            gemm_bt<0, 3><<<dim3(MT, 2), 256, 0, stream>>>(
                h, nullptr, nullptr, W2T + 512, zerob, z, z,
                MREAL, 512, 256, 1024, 256);
    }
    // LN2 in place
    ln_rows<0><<<(MREAL + 3) / 4, 256, 0, stream>>>(z, g2, be2, z, nullptr, MREAL);
}

// Round 5
// 607.106 us; speedup vs baseline: 1.2374x; 1.0582x over previous
//
#include <hip/hip_runtime.h>

// ---------------------------------------------------------------------------
// DeformableTransformerEncoderLayer on MI355X (gfx950)
// B=4, LQ=13294, DM=256, DFFN=1024, NL=4, NH=8, NP=4, HD=32
// M = 53176 rows, padded tiles to Mp = 53248 = 416*128.
// Round 5:
//  - sample_k: branchless bilinear (4 corner loads in flight), vectorized
//    offset/logit loads, softmax fused in-thread (softmax kernel removed).
//  - GEMMs with bf16 A (G4,G5,G6) stage via global_load_lds width=16.
// Pipeline:
//   G1: value_h = bf16(src) @ WvT + bv        (head-major scatter epilogue)
//   G2: offaw   = bf16(src+pos) @ [Ws|Wa]T + [bs|ba]  (bf16 logits, N=384)
//   sample:     attn_bf = MSDeformAttn(value_h, offaw, refp)  (softmax inside)
//   G4: z(d_out) = src + attn_bf @ WoT + bo   (fp32 + resid)
//   LN1: x_bf <- LN(z)                        (bf16, overlays value_h)
//   2x { G5p: h = relu(x_bf @ W1T[p] + b1[p])     (h overlays offaw+attn)
//        G6p: z = resid + h @ W2T[:,p] (+b2 on p0; resid = x_bf on p0 else z) }
//   LN2: d_out = LN(z) in place
// Workspace ~97 MB.
// ---------------------------------------------------------------------------

#define LQn   13294
#define MREAL 53176
#define MP    53248
#define MT    416

typedef __attribute__((ext_vector_type(8))) short short8;
typedef __attribute__((ext_vector_type(4))) short short4v;
typedef __attribute__((ext_vector_type(4))) float f32x4;

__device__ __forceinline__ short f2bf(float f) {
    unsigned u = __float_as_uint(f);
    unsigned r = (u + 0x7FFFu + ((u >> 16) & 1u)) >> 16;  // RNE
    return (short)r;
}
__device__ __forceinline__ float bf2f(short b) {
    return __uint_as_float(((unsigned)(unsigned short)b) << 16);
}

#define GLOAD16(gp, lp)                                                        \
    __builtin_amdgcn_global_load_lds(                                          \
        (const __attribute__((address_space(1))) void*)(gp),                   \
        (__attribute__((address_space(3))) void*)(lp), 16, 0, 0)

// ---------------------------------------------------------------------------
__global__ __launch_bounds__(256) void transpose_w(const float* __restrict__ W,
                                                   short* __restrict__ WT,
                                                   int K, int N) {
    const int i = blockIdx.x * 256 + threadIdx.x;
    if (i >= K * N) return;
    const int n = i / K, k = i - n * K;
    WT[i] = f2bf(W[(size_t)k * N + n]);
}

__global__ void prep_small_k(const float* __restrict__ bs,
                             const float* __restrict__ ba,
                             float* __restrict__ bsa,
                             float* __restrict__ zerob) {
    const int t = threadIdx.x;
    if (t < 256) { bsa[t] = bs[t]; zerob[t] = 0.f; }
    else if (t < 384) bsa[t] = ba[t - 256];
}

// ---------------------------------------------------------------------------
// bf16 MFMA GEMM. 128x128 tile, BK=32, 4 waves, 16x16x32 MFMA.
// SRC: 0 = A bf16[M][K] staged via global_load_lds; 1 = A fp32 (convert);
//      2 = A+A2 fp32 (q=src+pos)  (1/2 use reg staging)
// EPI: 1 = bf16+bias; 2 = relu->bf16+bias; 3 = fp32+bias+fp32 resid;
//      4 = fp32+bias+bf16 resid; 5 = bf16+bias scattered head-major
// ---------------------------------------------------------------------------
template <int SRC>
__device__ __forceinline__ short8 lda8(const float* Af, const float* A2,
                                       size_t idx) {
    const float4 lo = *(const float4*)(Af + idx);
    const float4 hi = *(const float4*)(Af + idx + 4);
    float v[8] = {lo.x, lo.y, lo.z, lo.w, hi.x, hi.y, hi.z, hi.w};
    if constexpr (SRC == 2) {
        const float4 lo2 = *(const float4*)(A2 + idx);
        const float4 hi2 = *(const float4*)(A2 + idx + 4);
        v[0] += lo2.x; v[1] += lo2.y; v[2] += lo2.z; v[3] += lo2.w;
        v[4] += hi2.x; v[5] += hi2.y; v[6] += hi2.z; v[7] += hi2.w;
    }
    short8 r;
#pragma unroll
    for (int j = 0; j < 8; ++j) r[j] = f2bf(v[j]);
    return r;
}

template <int SRC, int EPI>
__global__ __launch_bounds__(256) void gemm_bt(const short* __restrict__ Ab,
                                               const float* __restrict__ Af,
                                               const float* __restrict__ A2,
                                               const short* __restrict__ BT,
                                               const float* __restrict__ bias,
                                               const void* resid,
                                               void* C,
                                               int M, int K, int N,
                                               int ldb, int ldc) {
    __shared__ short lA[128 * 32];
    __shared__ short lB[128 * 32];
    const int t = threadIdx.x;
    const int m0 = blockIdx.x * 128, n0 = blockIdx.y * 128;
    const int wid = t >> 6, lane = t & 63;
    const int wr = wid >> 1, wc = wid & 1;
    const int quad = lane >> 4, l16 = lane & 15;

    f32x4 acc[4][4];
#pragma unroll
    for (int i = 0; i < 4; ++i)
#pragma unroll
        for (int j = 0; j < 4; ++j) acc[i][j] = (f32x4){0.f, 0.f, 0.f, 0.f};

    // reg-staging geometry (SRC 1/2)
    const int ar0 = t >> 2, ac0 = (t & 3) * 8;
    const int ar1 = ar0 + 64, ac1 = ac0;
    const int arow0 = min(m0 + ar0, M - 1);
    const int arow1 = min(m0 + ar1, M - 1);
    // gload geometry (SRC 0): wave wid stages rows [wid*32, wid*32+32)
    const int grow = wid * 32 + (lane >> 2);
    const int gcol = (lane & 3) * 8;

    for (int k0 = 0; k0 < K; k0 += 32) {
        if constexpr (SRC == 0) {
            __syncthreads();  // prior iteration's ds_reads complete
            GLOAD16(Ab + (size_t)(m0 + grow) * K + k0 + gcol,
                    &lA[(wid * 32) * 32]);
            GLOAD16(Ab + (size_t)(m0 + grow + 16) * K + k0 + gcol,
                    &lA[(wid * 32 + 16) * 32]);
            GLOAD16(BT + (size_t)(n0 + grow) * ldb + k0 + gcol,
                    &lB[(wid * 32) * 32]);
            GLOAD16(BT + (size_t)(n0 + grow + 16) * ldb + k0 + gcol,
                    &lB[(wid * 32 + 16) * 32]);
            __syncthreads();  // vmcnt(0) drained by compiler before barrier
        } else {
            const short8 va0 = lda8<SRC>(Af, A2, (size_t)arow0 * K + k0 + ac0);
            const short8 va1 = lda8<SRC>(Af, A2, (size_t)arow1 * K + k0 + ac1);
            const short8 vb0 = *(const short8*)(BT + (size_t)(n0 + ar0) * ldb + k0 + ac0);
            const short8 vb1 = *(const short8*)(BT + (size_t)(n0 + ar1) * ldb + k0 + ac1);
            __syncthreads();
            *(short8*)&lA[ar0 * 32 + ac0] = va0;
            *(short8*)&lA[ar1 * 32 + ac1] = va1;
            *(short8*)&lB[ar0 * 32 + ac0] = vb0;
            *(short8*)&lB[ar1 * 32 + ac1] = vb1;
            __syncthreads();
        }
        short8 af[4], bfr[4];
#pragma unroll
        for (int mi = 0; mi < 4; ++mi)
            af[mi] = *(const short8*)&lA[(wr * 64 + mi * 16 + l16) * 32 + quad * 8];
#pragma unroll
        for (int ni = 0; ni < 4; ++ni)
            bfr[ni] = *(const short8*)&lB[(wc * 64 + ni * 16 + l16) * 32 + quad * 8];
#pragma unroll
        for (int mi = 0; mi < 4; ++mi)
#pragma unroll
            for (int ni = 0; ni < 4; ++ni)
                acc[mi][ni] = __builtin_amdgcn_mfma_f32_16x16x32_bf16(
                    af[mi], bfr[ni], acc[mi][ni], 0, 0, 0);
    }

#pragma unroll
    for (int ni = 0; ni < 4; ++ni) {
        const int gc = n0 + wc * 64 + ni * 16 + l16;
        const float bia = bias[gc];
#pragma unroll
        for (int mi = 0; mi < 4; ++mi) {
#pragma unroll
            for (int r = 0; r < 4; ++r) {
                const int gr = m0 + wr * 64 + mi * 16 + quad * 4 + r;
                if (gr < M) {
                    float v = acc[mi][ni][r] + bia;
                    if (EPI == 3) {
                        v += ((const float*)resid)[(size_t)gr * ldc + gc];
                        ((float*)C)[(size_t)gr * ldc + gc] = v;
                    } else if (EPI == 4) {
                        v += bf2f(((const short*)resid)[(size_t)gr * ldc + gc]);
                        ((float*)C)[(size_t)gr * ldc + gc] = v;
                    } else if (EPI == 5) {
                        // head-major scatter: [B][NH][LQ][HD]
                        const int b = gr / LQn, s = gr - b * LQn;
                        const int hh = gc >> 5, d = gc & 31;
                        ((short*)C)[(((size_t)b * 8 + hh) * LQn + s) * 32 + d] = f2bf(v);
                    } else {
                        if (EPI == 2) v = fmaxf(v, 0.f);
                        ((short*)C)[(size_t)gr * ldc + gc] = f2bf(v);
                    }
                }
            }
        }
    }
}

// ---------------------------------------------------------------------------
// MS deformable sampling, head-major value [B][NH][LQ][HD].
// 4 threads per (row, head); each owns 8 of 32 dims. Branchless bilinear:
// clamped indices + zeroed weights; 4 corner loads issued together.
// Softmax over the 16 attention logits fused (computed per-thread).
// ---------------------------------------------------------------------------
__global__ __launch_bounds__(256) void sample_k(const short* __restrict__ value,
                                                const short* __restrict__ offaw,
                                                const float* __restrict__ refp,
                                                short* __restrict__ attn) {
    const int t = blockIdx.x * 256 + threadIdx.x;
    const int grp = t >> 2, sub = t & 3;
    if (grp >= MREAL * 8) return;
    const int row = grp >> 3, h = grp & 7;
    const int b = row / LQn;
    const int L_[4] = {100, 50, 25, 13};
    const int O_[4] = {0, 10000, 12500, 13125};
    const short* op = offaw + (size_t)row * 384 + h * 32;
    const short* ap = offaw + (size_t)row * 384 + 256 + h * 16;

    // fused softmax over 16 logits (fp32 weights)
    float wgt[16];
    {
        const short8 a0 = *(const short8*)ap;
        const short8 a1 = *(const short8*)(ap + 8);
#pragma unroll
        for (int j = 0; j < 8; ++j) { wgt[j] = bf2f(a0[j]); wgt[j + 8] = bf2f(a1[j]); }
        float m = wgt[0];
#pragma unroll
        for (int j = 1; j < 16; ++j) m = fmaxf(m, wgt[j]);
        float s = 0.f;
#pragma unroll
        for (int j = 0; j < 16; ++j) { wgt[j] = __expf(wgt[j] - m); s += wgt[j]; }
        const float inv = 1.f / s;
#pragma unroll
        for (int j = 0; j < 16; ++j) wgt[j] *= inv;
    }

    const float4 r01 = ((const float4*)(refp + (size_t)row * 8))[0];
    const float4 r23 = ((const float4*)(refp + (size_t)row * 8))[1];
    const float rxs[4] = {r01.x, r01.z, r23.x, r23.z};
    const float rys[4] = {r01.y, r01.w, r23.y, r23.w};

    const short* vplane = value + ((size_t)(b * 8 + h) * LQn) * 32 + sub * 8;
    float acc[8];
#pragma unroll
    for (int j = 0; j < 8; ++j) acc[j] = 0.f;

#pragma unroll
    for (int l = 0; l < 4; ++l) {
        const int L = L_[l];
        const float Lf = (float)L;
        const short* vlev = vplane + (size_t)O_[l] * 32;
        const short8 ov = *(const short8*)(op + l * 8);
        const float rx = rxs[l], ry = rys[l];
#pragma unroll
        for (int p = 0; p < 4; ++p) {
            const float x = fmaf(rx, Lf, bf2f(ov[p * 2 + 0]) - 0.5f);
            const float y = fmaf(ry, Lf, bf2f(ov[p * 2 + 1]) - 0.5f);
            const float xf = floorf(x), yf = floorf(y);
            const int ix = (int)xf, iy = (int)yf;
            const float fx = x - xf, fy = y - yf;
            const float aw = wgt[l * 4 + p];
            const float vx0 = ((unsigned)ix < (unsigned)L) ? 1.f : 0.f;
            const float vx1 = ((unsigned)(ix + 1) < (unsigned)L) ? 1.f : 0.f;
            const float vy0 = ((unsigned)iy < (unsigned)L) ? 1.f : 0.f;
            const float vy1 = ((unsigned)(iy + 1) < (unsigned)L) ? 1.f : 0.f;
            const float gx0 = (1.f - fx) * aw, gx1 = fx * aw;
            const float w00 = gx0 * (1.f - fy) * vx0 * vy0;
            const float w10 = gx1 * (1.f - fy) * vx1 * vy0;
            const float w01 = gx0 * fy * vx0 * vy1;
            const float w11 = gx1 * fy * vx1 * vy1;
            const int ix0 = min(max(ix, 0), L - 1);
            const int ix1 = min(max(ix + 1, 0), L - 1);
            const int iy0 = min(max(iy, 0), L - 1);
            const int iy1 = min(max(iy + 1, 0), L - 1);
            // 4 independent loads -> all in flight together
            const short8 v00 = *(const short8*)(vlev + ((size_t)iy0 * L + ix0) * 32);
            const short8 v10 = *(const short8*)(vlev + ((size_t)iy0 * L + ix1) * 32);
            const short8 v01 = *(const short8*)(vlev + ((size_t)iy1 * L + ix0) * 32);
            const short8 v11 = *(const short8*)(vlev + ((size_t)iy1 * L + ix1) * 32);
#pragma unroll
            for (int j = 0; j < 8; ++j)
                acc[j] += w00 * bf2f(v00[j]) + w10 * bf2f(v10[j]) +
                          w01 * bf2f(v01[j]) + w11 * bf2f(v11[j]);
        }
    }
    short8 o;
#pragma unroll
    for (int j = 0; j < 8; ++j) o[j] = f2bf(acc[j]);
    *(short8*)(attn + (size_t)row * 256 + h * 32 + sub * 8) = o;
}

// ---------------------------------------------------------------------------
// Row LayerNorm over 256 cols. One wave per row, float4 per lane.
// OUT_BF=0: fp32 out (in-place safe). OUT_BF=1: bf16 out only.
// ---------------------------------------------------------------------------
template <int OUT_BF>
__global__ __launch_bounds__(256) void ln_rows(const float* in,
                                               const float* __restrict__ g,
                                               const float* __restrict__ be,
                                               float* outf, short* outb, int M) {
    const int row = blockIdx.x * 4 + (threadIdx.x >> 6);
    if (row >= M) return;
    const int lane = threadIdx.x & 63;
    const float4 v = ((const float4*)(in + (size_t)row * 256))[lane];
    float s = v.x + v.y + v.z + v.w;
#pragma unroll
    for (int o = 32; o > 0; o >>= 1) s += __shfl_xor(s, o);
    const float mean = s * (1.0f / 256.0f);
    const float dx = v.x - mean, dy = v.y - mean, dz = v.z - mean, dw = v.w - mean;
    float q = dx * dx + dy * dy + dz * dz + dw * dw;
#pragma unroll
    for (int o = 32; o > 0; o >>= 1) q += __shfl_xor(q, o);
    const float rstd = rsqrtf(q * (1.0f / 256.0f) + 1e-5f);
    const float4 gv = ((const float4*)g)[lane];
    const float4 bv = ((const float4*)be)[lane];
    float4 o4;
    o4.x = dx * rstd * gv.x + bv.x;
    o4.y = dy * rstd * gv.y + bv.y;
    o4.z = dz * rstd * gv.z + bv.z;
    o4.w = dw * rstd * gv.w + bv.w;
    if (OUT_BF) {
        short4v ob;
        ob.x = f2bf(o4.x); ob.y = f2bf(o4.y); ob.z = f2bf(o4.z); ob.w = f2bf(o4.w);
        ((short4v*)(outb + (size_t)row * 256))[lane] = ob;
    } else {
        ((float4*)(outf + (size_t)row * 256))[lane] = o4;
    }
}

// ---------------------------------------------------------------------------
extern "C" void kernel_launch(void* const* d_in, const int* in_sizes, int n_in,
                              void* d_out, int out_size, void* d_ws, size_t ws_size,
                              hipStream_t stream) {
    (void)in_sizes; (void)n_in; (void)out_size; (void)ws_size;
    const float* src  = (const float*)d_in[0];
    const float* pos  = (const float*)d_in[1];
    const float* refp = (const float*)d_in[2];
    const float* Wv = (const float*)d_in[5];
    const float* bv = (const float*)d_in[6];
    const float* Ws = (const float*)d_in[7];
    const float* bs = (const float*)d_in[8];
    const float* Wa = (const float*)d_in[9];
    const float* ba = (const float*)d_in[10];
    const float* Wo = (const float*)d_in[11];
    const float* bo = (const float*)d_in[12];
    const float* W1 = (const float*)d_in[13];
    const float* b1 = (const float*)d_in[14];
    const float* W2 = (const float*)d_in[15];
    const float* b2 = (const float*)d_in[16];
    const float* g1 = (const float*)d_in[17];
    const float* be1 = (const float*)d_in[18];
    const float* g2 = (const float*)d_in[19];
    const float* be2 = (const float*)d_in[20];

    char* ws = (char*)d_ws;
    size_t off = 0;
    auto take = [&](size_t bytes) {
        char* p = ws + off;
        off += (bytes + 255) & ~(size_t)255;
        return p;
    };
    short* WvT  = (short*)take(256 * 256 * 2);
    short* WsaT = (short*)take(384 * 256 * 2);
    short* WoT  = (short*)take(256 * 256 * 2);
    short* W1T  = (short*)take(1024 * 256 * 2);
    short* W2T  = (short*)take(256 * 1024 * 2);
    float* bsa  = (float*)take(384 * 4);
    float* zerob = (float*)take(256 * 4);
    short* value_h = (short*)take((size_t)MP * 256 * 2);  // head-major value; later x_bf
    short* offaw   = (short*)take((size_t)MP * 384 * 2);  // later h part 1
    short* attn_bf = (short*)take((size_t)MP * 256 * 2);  // later h part 2
    // total ~96.9 MB

    short* x_bf = value_h;         // after sampling, value dead
    short* h    = offaw;           // h half 54.5 MB spans offaw(40.9)+attn(27.3)
    float* z    = (float*)d_out;

    // Weight prep
    transpose_w<<<(256 * 256) / 256, 256, 0, stream>>>(Wv, WvT, 256, 256);
    transpose_w<<<(256 * 256) / 256, 256, 0, stream>>>(Ws, WsaT, 256, 256);
    transpose_w<<<(256 * 128) / 256, 256, 0, stream>>>(Wa, WsaT + 256 * 256, 256, 128);
    transpose_w<<<(256 * 256) / 256, 256, 0, stream>>>(Wo, WoT, 256, 256);
    transpose_w<<<(256 * 1024) / 256, 256, 0, stream>>>(W1, W1T, 256, 1024);
    transpose_w<<<(1024 * 256) / 256, 256, 0, stream>>>(W2, W2T, 1024, 256);
    prep_small_k<<<1, 384, 0, stream>>>(bs, ba, bsa, zerob);

    // G1: value (head-major) = bf16(src) @ WvT + bv
    gemm_bt<1, 5><<<dim3(MT, 2), 256, 0, stream>>>(
        nullptr, src, nullptr, WvT, bv, nullptr, value_h, MREAL, 256, 256, 256, 256);
    // G2: offaw = bf16(src+pos) @ WsaT + bsa  (logits; softmax fused in sample)
    gemm_bt<2, 1><<<dim3(MT, 3), 256, 0, stream>>>(
        nullptr, src, pos, WsaT, bsa, nullptr, offaw, MREAL, 256, 384, 256, 384);
    // Deformable sampling (softmax inside)
    sample_k<<<(MREAL * 32) / 256, 256, 0, stream>>>(value_h, offaw, refp, attn_bf);
    // G4: z = src + attn @ WoT + bo
    gemm_bt<0, 3><<<dim3(MT, 2), 256, 0, stream>>>(
        attn_bf, nullptr, nullptr, WoT, bo, src, z, MREAL, 256, 256, 256, 256);
    // LN1: x_bf = LN(z)   (bf16 only)
    ln_rows<1><<<(MREAL + 3) / 4, 256, 0, stream>>>(z, g1, be1, nullptr, x_bf, MREAL);
    // FFN in 2 half-passes over DFFN
    for (int p = 0; p < 2; ++p) {
        gemm_bt<0, 2><<<dim3(MT, 4), 256, 0, stream>>>(
            x_bf, nullptr, nullptr, W1T + (size_t)p * 512 * 256, b1 + p * 512,
            nullptr, h, MREAL, 256, 512, 256, 512);
        if (p == 0)
            gemm_bt<0, 4><<<dim3(MT, 2), 256, 0, stream>>>(
                h, nullptr, nullptr, W2T + 0, b2, x_bf, z,
                MREAL, 512, 256, 1024, 256);
        else
            gemm_bt<0, 3><<<dim3(MT, 2), 256, 0, stream>>>(
                h, nullptr, nullptr, W2T + 512, zerob, z, z,
                MREAL, 512, 256, 1024, 256);
    }
    // LN2 in place
    ln_rows<0><<<(MREAL + 3) / 4, 256, 0, stream>>>(z, g2, be2, z, nullptr, MREAL);
}